// Round 11
// baseline (284.951 us; speedup 1.0000x reference)
//
#include <hip/hip_runtime.h>
#include <hip/hip_bf16.h>
#include <math.h>
#include <stdint.h>

// Problem constants
#define T_TOK 1024   // B*S
#define H_DIM 1024
#define I_DIM 4096
#define E_NUM 8
#define NSLOT (2 * T_TOK)
#define MAXT 24             // max 128-row m-tiles across experts (padded)

typedef __attribute__((ext_vector_type(8))) short bf16x8;
typedef __attribute__((ext_vector_type(4))) float f32x4;

#define MFMA_BF16(a, b, c) __builtin_amdgcn_mfma_f32_16x16x32_bf16(a, b, c, 0, 0, 0)

__device__ __forceinline__ short f2bf(float f) {
  union { float f; unsigned u; } x; x.f = f;
  unsigned r = (x.u + 0x7fffu + ((x.u >> 16) & 1u)) >> 16;
  return (short)r;
}

// HW packed f32->bf16 (RNE), gfx950
__device__ __forceinline__ int cvtpk(float a, float b) {
  int r;
  asm("v_cvt_pk_bf16_f32 %0, %1, %2" : "=v"(r) : "v"(a), "v"(b));
  return r;
}

typedef __attribute__((address_space(3))) unsigned int as3_u32;
typedef const __attribute__((address_space(1))) unsigned int as1_u32c;
__device__ __forceinline__ void glds16(const void* g, void* l) {
  __builtin_amdgcn_global_load_lds((as1_u32c*)g, (as3_u32*)l, 16, 0, 0);
}

union BBCast { int4 i4; bf16x8 v; };

// ---------------- K1: LayerNorm + router + top2 + residual prefill ----------------
__global__ __launch_bounds__(256) void k_pre(
    const float* __restrict__ x, const float* __restrict__ ln_w,
    const float* __restrict__ ln_b, const float* __restrict__ Wr,
    const float* __restrict__ br,
    short* __restrict__ xln, int* __restrict__ sel_e, float* __restrict__ sel_w,
    float* __restrict__ probs, float* __restrict__ out) {
  __shared__ float sx[H_DIM];
  __shared__ float redS[8];
  __shared__ float slog[E_NUM];

  const int t = blockIdx.x;
  const int tid = threadIdx.x;
  const int lane = tid & 63, wid = tid >> 6;

  float4 v = ((const float4*)(x + (size_t)t * H_DIM))[tid];
  ((float4*)(out + (size_t)t * H_DIM))[tid] = v;   // residual prefill
  float s = v.x + v.y + v.z + v.w;
  float ss = v.x * v.x + v.y * v.y + v.z * v.z + v.w * v.w;
  for (int o = 32; o > 0; o >>= 1) { s += __shfl_down(s, o); ss += __shfl_down(ss, o); }
  if (lane == 0) { redS[wid] = s; redS[4 + wid] = ss; }
  __syncthreads();
  float st = redS[0] + redS[1] + redS[2] + redS[3];
  float sst = redS[4] + redS[5] + redS[6] + redS[7];
  float mu = st * (1.0f / H_DIM);
  float var = sst * (1.0f / H_DIM) - mu * mu;
  float rs = rsqrtf(var + 1e-5f);

  float4 lw = ((const float4*)ln_w)[tid];
  float4 lb = ((const float4*)ln_b)[tid];
  float4 xn;
  xn.x = (v.x - mu) * rs * lw.x + lb.x;
  xn.y = (v.y - mu) * rs * lw.y + lb.y;
  xn.z = (v.z - mu) * rs * lw.z + lb.z;
  xn.w = (v.w - mu) * rs * lw.w + lb.w;
  sx[4 * tid + 0] = xn.x; sx[4 * tid + 1] = xn.y;
  sx[4 * tid + 2] = xn.z; sx[4 * tid + 3] = xn.w;
  short4 s4;
  s4.x = f2bf(xn.x); s4.y = f2bf(xn.y); s4.z = f2bf(xn.z); s4.w = f2bf(xn.w);
  ((short4*)(xln + (size_t)t * H_DIM))[tid] = s4;
  __syncthreads();

  for (int e = 2 * wid; e < 2 * wid + 2; ++e) {
    float p = 0.f;
    for (int h = lane; h < H_DIM; h += 64) p += sx[h] * Wr[e * H_DIM + h];
    for (int o = 32; o > 0; o >>= 1) p += __shfl_down(p, o);
    if (lane == 0) slog[e] = p + br[e];
  }
  __syncthreads();

  if (tid == 0) {
    float lg[E_NUM];
    for (int e = 0; e < E_NUM; ++e) lg[e] = slog[e];
    int i0 = 0;
    for (int e = 1; e < E_NUM; ++e) if (lg[e] > lg[i0]) i0 = e;
    int i1 = (i0 == 0) ? 1 : 0;
    for (int e = 0; e < E_NUM; ++e) if (e != i0 && lg[e] > lg[i1]) i1 = e;
    float w1e = __expf(lg[i1] - lg[i0]);
    float den = 1.f + w1e;
    sel_e[2 * t] = i0; sel_w[2 * t] = 1.f / den;
    sel_e[2 * t + 1] = i1; sel_w[2 * t + 1] = w1e / den;
    float se = 0.f, pe[E_NUM];
    for (int e = 0; e < E_NUM; ++e) { pe[e] = __expf(lg[e] - lg[i0]); se += pe[e]; }
    float inv = 1.f / se;
    for (int e = 0; e < E_NUM; ++e) probs[t * E_NUM + e] = pe[e] * inv;
  }
}

// ---------------- K2: slot assignment + counts + tile table + loss ----------------
__global__ __launch_bounds__(512) void k_route(
    const int* __restrict__ sel_e, const float* __restrict__ sel_w,
    const float* __restrict__ probs,
    int* __restrict__ counts, int* __restrict__ basep,
    int* __restrict__ tile_e, int* __restrict__ tile_m0, int* __restrict__ ntiles,
    int* __restrict__ tlist, int* __restrict__ sel_idx,
    float* __restrict__ wslot, float* __restrict__ loss_out) {
  const int wid = threadIdx.x >> 6;
  const int lane = threadIdx.x & 63;
  __shared__ int scnt[E_NUM];
  __shared__ float susage[E_NUM];

  int cnt = 0;
  for (int s0 = 0; s0 < NSLOT; s0 += 64) {
    int s = s0 + lane;
    bool m = (sel_e[s] == wid);
    unsigned long long mk = __ballot(m);
    int pre = __popcll(mk & ((1ULL << lane) - 1ULL));
    if (m) {
      int idx = cnt + pre;
      sel_idx[s] = idx;
      tlist[wid * T_TOK + idx] = s >> 1;
      wslot[wid * T_TOK + idx] = sel_w[s];
    }
    cnt += __popcll(mk);
  }
  if (lane == 0) scnt[wid] = cnt;

  float u = 0.f;
  for (int t = lane; t < T_TOK; t += 64) u += probs[t * E_NUM + wid];
  for (int o = 32; o > 0; o >>= 1) u += __shfl_down(u, o);
  if (lane == 0) susage[wid] = u * (1.0f / T_TOK);
  __syncthreads();

  if (threadIdx.x == 0) {
    int b = 0, nt = 0;
    for (int e = 0; e < E_NUM; ++e) {
      basep[e] = b; counts[e] = scnt[e];
      int te = (scnt[e] + 127) >> 7;
      for (int i = 0; i < te && nt < MAXT; ++i) {
        tile_e[nt] = e; tile_m0[nt] = i * 128; ++nt;
      }
      b += te * 128;
    }
    ntiles[0] = nt;
    float sq = 0.f;
    for (int e = 0; e < E_NUM; ++e) sq += susage[e] * susage[e];
    *loss_out = (float)E_NUM * sq - 1.0f;
  }
}

// ---------------- K3: GEMM1 — A bf16 gathered, B raw f32 via glds, cvt-on-read ----------------
// 128x128, BK=32, 4 waves 2x2. LDS: A 3x8KB + B(f32) 3x16KB = 72KB (2 blocks/CU).
// B global source pre-swizzled per 16B granule (g ^= row&7) so swizzled-read
// b128 fragments are conflict-light. Fragments converted with v_cvt_pk_bf16_f32.
__global__ __launch_bounds__(256) void k_ffn1(
    const short* __restrict__ xln, const float* __restrict__ W1,
    const float* __restrict__ b1, const int* __restrict__ counts,
    const int* __restrict__ basep,
    const int* __restrict__ tile_e, const int* __restrict__ tile_m0,
    const int* __restrict__ ntiles, const int* __restrict__ tlist,
    short* __restrict__ a_buf) {
  const int bid = blockIdx.x;
  const int tileid = bid >> 5;
  if (tileid >= ntiles[0]) return;
  const int e = tile_e[tileid];
  const int m0 = tile_m0[tileid];
  const int cnt = counts[e];
  const int n0 = (bid & 31) * 128;

  __shared__ __align__(16) short As[3][128 * 32];   // bf16 [row][32]
  __shared__ __align__(16) float Bsf[3][128 * 32];  // f32 [row][32], granules swizzled

  const int tid = threadIdx.x;
  const int lane = tid & 63, wid = tid >> 6;
  const int wr = wid >> 1, wc = wid & 1;
  const int fr = lane & 15, fq = lane >> 4;

  int r0 = m0 + (tid >> 2); if (r0 >= cnt) r0 = cnt - 1;
  int r1 = m0 + 64 + (tid >> 2); if (r1 >= cnt) r1 = cnt - 1;
  const short* ag0 = xln + (size_t)tlist[e * T_TOK + r0] * H_DIM + (tid & 3) * 8;
  const short* ag1 = xln + (size_t)tlist[e * T_TOK + r1] * H_DIM + (tid & 3) * 8;

  // B: thread stages rows (tid>>3)+q*32, granule g=(tid&7)^((tid>>3)&7)
  const int bswz = (tid & 7) ^ ((tid >> 3) & 7);
  const float* bg = W1 + ((size_t)e * I_DIM + n0 + (tid >> 3)) * H_DIM + bswz * 4;

  f32x4 acc[4][4];
#pragma unroll
  for (int i = 0; i < 4; ++i)
#pragma unroll
    for (int j = 0; j < 4; ++j) acc[i][j] = (f32x4)0.f;

#define STAGE(kt, buf)                                              \
  {                                                                 \
    glds16(ag0 + (kt) * 32, &As[buf][tid * 8]);                     \
    glds16(ag1 + (kt) * 32, &As[buf][(256 + tid) * 8]);             \
    _Pragma("unroll") for (int q = 0; q < 4; ++q)                   \
        glds16(bg + (size_t)q * (32 * H_DIM) + (kt) * 32,           \
               &Bsf[buf][(q * 256 + tid) * 4]);                     \
  }

  STAGE(0, 0);
  STAGE(1, 1);

  const int KT = H_DIM / 32;
  for (int kt = 0; kt < KT; ++kt) {
    if (kt == KT - 1) {
      asm volatile("s_waitcnt vmcnt(0)" ::: "memory");
    } else {
      asm volatile("s_waitcnt vmcnt(6)" ::: "memory");
    }
    __builtin_amdgcn_s_barrier();
    if (kt + 2 < KT) STAGE(kt + 2, (kt + 2) % 3);
    const int cb = kt % 3;
    bf16x8 af[4], bb[4];
#pragma unroll
    for (int mi = 0; mi < 4; ++mi)
      af[mi] = *(const bf16x8*)&As[cb][(wr * 64 + mi * 16 + fr) * 32 + fq * 8];
#pragma unroll
    for (int ni = 0; ni < 4; ++ni) {
      const int row = wc * 64 + ni * 16 + fr;
      const int sw = row & 7;
      const char* bbase = (const char*)&Bsf[cb][0] + row * 128;
      f32x4 lo = *(const f32x4*)(bbase + (((fq * 2) ^ sw) * 16));
      f32x4 hi = *(const f32x4*)(bbase + (((fq * 2 + 1) ^ sw) * 16));
      BBCast c;
      c.i4.x = cvtpk(lo[0], lo[1]); c.i4.y = cvtpk(lo[2], lo[3]);
      c.i4.z = cvtpk(hi[0], hi[1]); c.i4.w = cvtpk(hi[2], hi[3]);
      bb[ni] = c.v;
    }
#pragma unroll
    for (int mi = 0; mi < 4; ++mi)
#pragma unroll
      for (int ni = 0; ni < 4; ++ni)
        acc[mi][ni] = MFMA_BF16(af[mi], bb[ni], acc[mi][ni]);
  }
#undef STAGE

  // epilogue: GELU, a_buf tile-packed [T][i>>5][r][i&31]
  const size_t T1 = (size_t)(basep[e] + m0) >> 7;
  short* abase = a_buf + T1 * 524288;
  float b1v[4];
#pragma unroll
  for (int ni = 0; ni < 4; ++ni)
    b1v[ni] = b1[e * I_DIM + n0 + wc * 64 + ni * 16 + fr];
#pragma unroll
  for (int mi = 0; mi < 4; ++mi)
#pragma unroll
    for (int j = 0; j < 4; ++j) {
      int r = wr * 64 + mi * 16 + fq * 4 + j;
      if (m0 + r < cnt) {
#pragma unroll
        for (int ni = 0; ni < 4; ++ni) {
          int colg = n0 + wc * 64 + ni * 16 + fr;
          float vv = acc[mi][ni][j] + b1v[ni];
          float g = 0.5f * vv * (1.0f + erff(vv * 0.70710678118654752f));
          abase[(size_t)(colg >> 5) * 4096 + r * 32 + (colg & 31)] = f2bf(g);
        }
      }
    }
}

// ---------------- K4: GEMM2 — A tile-packed bf16, B raw f32, split-K=4, atomics ----------------
__global__ __launch_bounds__(256) void k_ffn2(
    const short* __restrict__ a_buf, const float* __restrict__ W2,
    const float* __restrict__ b2, const int* __restrict__ counts,
    const int* __restrict__ basep,
    const int* __restrict__ tile_e, const int* __restrict__ tile_m0,
    const int* __restrict__ ntiles, const int* __restrict__ tlist,
    const float* __restrict__ wslot, float* __restrict__ out) {
  const int bid = blockIdx.x;
  const int tileid = bid >> 5;
  if (tileid >= ntiles[0]) return;
  const int rem = bid & 31;
  const int kc = rem >> 3;
  const int n0 = (rem & 7) * 128;
  const int e = tile_e[tileid];
  const int m0 = tile_m0[tileid];
  const int cnt = counts[e];

  __shared__ __align__(16) short As[3][128 * 32];
  __shared__ __align__(16) float Bsf[3][128 * 32];

  const int tid = threadIdx.x;
  const int lane = tid & 63, wid = tid >> 6;
  const int wr = wid >> 1, wc = wid & 1;
  const int fr = lane & 15, fq = lane >> 4;

  const size_t T1 = (size_t)(basep[e] + m0) >> 7;
  const short* agp = a_buf + T1 * 524288 + (size_t)kc * 131072 + tid * 8;

  const int bswz = (tid & 7) ^ ((tid >> 3) & 7);
  const float* bg = W2 + ((size_t)e * H_DIM + n0 + (tid >> 3)) * I_DIM +
                    kc * 1024 + bswz * 4;

  f32x4 acc[4][4];
#pragma unroll
  for (int i = 0; i < 4; ++i)
#pragma unroll
    for (int j = 0; j < 4; ++j) acc[i][j] = (f32x4)0.f;

#define STAGE(kt, buf)                                              \
  {                                                                 \
    glds16(agp + (size_t)(kt) * 4096, &As[buf][tid * 8]);           \
    glds16(agp + (size_t)(kt) * 4096 + 2048,                        \
           &As[buf][(256 + tid) * 8]);                              \
    _Pragma("unroll") for (int q = 0; q < 4; ++q)                   \
        glds16(bg + (size_t)q * (32 * I_DIM) + (kt) * 32,           \
               &Bsf[buf][(q * 256 + tid) * 4]);                     \
  }

  STAGE(0, 0);
  STAGE(1, 1);

  const int KT = 32;   // 1024 K per split / 32
  for (int kt = 0; kt < KT; ++kt) {
    if (kt == KT - 1) {
      asm volatile("s_waitcnt vmcnt(0)" ::: "memory");
    } else {
      asm volatile("s_waitcnt vmcnt(6)" ::: "memory");
    }
    __builtin_amdgcn_s_barrier();
    if (kt + 2 < KT) STAGE(kt + 2, (kt + 2) % 3);
    const int cb = kt % 3;
    bf16x8 af[4], bb[4];
#pragma unroll
    for (int mi = 0; mi < 4; ++mi)
      af[mi] = *(const bf16x8*)&As[cb][(wr * 64 + mi * 16 + fr) * 32 + fq * 8];
#pragma unroll
    for (int ni = 0; ni < 4; ++ni) {
      const int row = wc * 64 + ni * 16 + fr;
      const int sw = row & 7;
      const char* bbase = (const char*)&Bsf[cb][0] + row * 128;
      f32x4 lo = *(const f32x4*)(bbase + (((fq * 2) ^ sw) * 16));
      f32x4 hi = *(const f32x4*)(bbase + (((fq * 2 + 1) ^ sw) * 16));
      BBCast c;
      c.i4.x = cvtpk(lo[0], lo[1]); c.i4.y = cvtpk(lo[2], lo[3]);
      c.i4.z = cvtpk(hi[0], hi[1]); c.i4.w = cvtpk(hi[2], hi[3]);
      bb[ni] = c.v;
    }
#pragma unroll
    for (int mi = 0; mi < 4; ++mi)
#pragma unroll
      for (int ni = 0; ni < 4; ++ni)
        acc[mi][ni] = MFMA_BF16(af[mi], bb[ni], acc[mi][ni]);
  }
#undef STAGE

  float b2v[4];
#pragma unroll
  for (int ni = 0; ni < 4; ++ni)
    b2v[ni] = 0.25f * b2[e * H_DIM + n0 + wc * 64 + ni * 16 + fr];
#pragma unroll
  for (int mi = 0; mi < 4; ++mi)
#pragma unroll
    for (int j = 0; j < 4; ++j) {
      int r = wr * 64 + mi * 16 + fq * 4 + j;
      if (m0 + r < cnt) {
        int tok = tlist[e * T_TOK + m0 + r];
        float w = wslot[e * T_TOK + m0 + r];
        float* orow = out + (size_t)tok * H_DIM;
#pragma unroll
        for (int ni = 0; ni < 4; ++ni) {
          int colg = n0 + wc * 64 + ni * 16 + fr;
          atomicAdd(&orow[colg], w * (acc[mi][ni][j] + b2v[ni]));
        }
      }
    }
}

extern "C" void kernel_launch(void* const* d_in, const int* in_sizes, int n_in,
                              void* d_out, int out_size, void* d_ws, size_t ws_size,
                              hipStream_t stream) {
  const float* hidden = (const float*)d_in[0];
  const float* ln_w = (const float*)d_in[1];
  const float* ln_b = (const float*)d_in[2];
  const float* Wr = (const float*)d_in[3];
  const float* br = (const float*)d_in[4];
  const float* W1 = (const float*)d_in[5];
  const float* b1 = (const float*)d_in[6];
  const float* W2 = (const float*)d_in[7];
  const float* b2 = (const float*)d_in[8];
  float* out = (float*)d_out;

  // workspace layout (bytes) — total ~26.4 MB
  char* w = (char*)d_ws;
  int* counts = (int*)(w + 0);
  int* basep = (int*)(w + 64);
  int* ntiles = (int*)(w + 128);
  int* tile_e = (int*)(w + 192);
  int* tile_m0 = (int*)(w + 320);
  float* probs = (float*)(w + 512);               // 32 KB
  int* tlist = (int*)(w + 33280);                 // 32 KB
  int* sel_e = (int*)(w + 66048);                 // 8 KB
  int* sel_idx = (int*)(w + 74240);               // 8 KB
  float* sel_w = (float*)(w + 82432);             // 8 KB
  float* wslot = (float*)(w + 90624);             // 8 KB
  short* xln = (short*)(w + 131072);              // 2 MB -> 2228224
  short* a_buf = (short*)(w + 2228224);           // 24 MB tile-packed

  k_pre<<<T_TOK, 256, 0, stream>>>(hidden, ln_w, ln_b, Wr, br, xln,
                                   sel_e, sel_w, probs, out);
  k_route<<<1, 512, 0, stream>>>(sel_e, sel_w, probs, counts, basep,
                                 tile_e, tile_m0, ntiles, tlist, sel_idx,
                                 wslot, out + (size_t)T_TOK * H_DIM);
  k_ffn1<<<MAXT * 32, 256, 0, stream>>>(
      xln, W1, b1, counts, basep, tile_e, tile_m0, ntiles, tlist, a_buf);
  k_ffn2<<<MAXT * 32, 256, 0, stream>>>(
      a_buf, W2, b2, counts, basep, tile_e, tile_m0, ntiles, tlist,
      wslot, out);
}

// Round 12
// 207.908 us; speedup vs baseline: 1.3706x; 1.3706x over previous
//
#include <hip/hip_runtime.h>
#include <hip/hip_bf16.h>
#include <math.h>
#include <stdint.h>

// Problem constants
#define T_TOK 1024   // B*S
#define H_DIM 1024
#define I_DIM 4096
#define E_NUM 8
#define NSLOT (2 * T_TOK)
#define MAXT 24             // max 128-row m-tiles across experts (padded)
#define SLOTP 3072          // padded slot capacity (2048 + 8*127 rounded up)

typedef __attribute__((ext_vector_type(8))) short bf16x8;
typedef __attribute__((ext_vector_type(4))) float f32x4;

#define MFMA_BF16(a, b, c) __builtin_amdgcn_mfma_f32_16x16x32_bf16(a, b, c, 0, 0, 0)

__device__ __forceinline__ short f2bf(float f) {
  union { float f; unsigned u; } x; x.f = f;
  unsigned r = (x.u + 0x7fffu + ((x.u >> 16) & 1u)) >> 16;
  return (short)r;
}
__device__ __forceinline__ int pack2bf(float a, float b) {
  return ((int)(unsigned short)f2bf(a)) | (((int)f2bf(b)) << 16);
}

typedef __attribute__((address_space(3))) unsigned int as3_u32;
typedef const __attribute__((address_space(1))) unsigned int as1_u32c;
__device__ __forceinline__ void glds16(const void* g, void* l) {
  __builtin_amdgcn_global_load_lds((as1_u32c*)g, (as3_u32*)l, 16, 0, 0);
}

union BBCast { int4 i4; bf16x8 v; };

// ---- cvt + tile-repack: src f32 [e][n][k] -> dst bf16 [e][n>>7][k>>5][n&127][k&31]
__device__ __forceinline__ void cvtpack_dev(const float* __restrict__ src,
                                            short* __restrict__ dst,
                                            int bid, int nb, int rsh, int csh) {
  const size_t total8 = ((size_t)E_NUM << (rsh + csh)) >> 3;
  const int kmask = (1 << (csh - 3)) - 1;
  const int nmask = (1 << rsh) - 1;
  for (size_t id = (size_t)bid * 256 + threadIdx.x; id < total8;
       id += (size_t)nb * 256) {
    int k8 = (int)(id & kmask);
    int n = (int)((id >> (csh - 3)) & nmask);
    int e = (int)(id >> (csh - 3 + rsh));
    int k = k8 << 3;
    size_t eoff = (size_t)e << (rsh + csh);
    const float* s = src + eoff + ((size_t)n << csh) + k;
    float4 a = *(const float4*)s;
    float4 b = *(const float4*)(s + 4);
    int4 p;
    p.x = pack2bf(a.x, a.y); p.y = pack2bf(a.z, a.w);
    p.z = pack2bf(b.x, b.y); p.w = pack2bf(b.z, b.w);
    size_t tile = ((size_t)(n >> 7) << (csh - 5)) + (k >> 5);
    *(int4*)(dst + eoff + tile * 4096 + ((n & 127) << 5) + (k & 31)) = p;
  }
}

// ---------------- K1: LayerNorm+router+top2+residual prefill, fused cvtW1 ----------------
__global__ __launch_bounds__(256) void k_pre(
    const float* __restrict__ x, const float* __restrict__ ln_w,
    const float* __restrict__ ln_b, const float* __restrict__ Wr,
    const float* __restrict__ br,
    short* __restrict__ xln, int* __restrict__ sel_e, float* __restrict__ sel_w,
    float* __restrict__ probs, float* __restrict__ out,
    const float* __restrict__ W1src, short* __restrict__ w1dst, int ncvt) {
  __shared__ float sx[H_DIM];
  __shared__ float redS[8];
  __shared__ float slog[E_NUM];

  if (blockIdx.x >= T_TOK) {
    cvtpack_dev(W1src, w1dst, blockIdx.x - T_TOK, ncvt, 12, 10);  // rows=I, cols=H
    return;
  }
  const int t = blockIdx.x;
  const int tid = threadIdx.x;
  const int lane = tid & 63, wid = tid >> 6;

  float4 v = ((const float4*)(x + (size_t)t * H_DIM))[tid];
  ((float4*)(out + (size_t)t * H_DIM))[tid] = v;   // residual prefill
  float s = v.x + v.y + v.z + v.w;
  float ss = v.x * v.x + v.y * v.y + v.z * v.z + v.w * v.w;
  for (int o = 32; o > 0; o >>= 1) { s += __shfl_down(s, o); ss += __shfl_down(ss, o); }
  if (lane == 0) { redS[wid] = s; redS[4 + wid] = ss; }
  __syncthreads();
  float st = redS[0] + redS[1] + redS[2] + redS[3];
  float sst = redS[4] + redS[5] + redS[6] + redS[7];
  float mu = st * (1.0f / H_DIM);
  float var = sst * (1.0f / H_DIM) - mu * mu;
  float rs = rsqrtf(var + 1e-5f);

  float4 lw = ((const float4*)ln_w)[tid];
  float4 lb = ((const float4*)ln_b)[tid];
  float4 xn;
  xn.x = (v.x - mu) * rs * lw.x + lb.x;
  xn.y = (v.y - mu) * rs * lw.y + lb.y;
  xn.z = (v.z - mu) * rs * lw.z + lb.z;
  xn.w = (v.w - mu) * rs * lw.w + lb.w;
  sx[4 * tid + 0] = xn.x; sx[4 * tid + 1] = xn.y;
  sx[4 * tid + 2] = xn.z; sx[4 * tid + 3] = xn.w;
  short4 s4;
  s4.x = f2bf(xn.x); s4.y = f2bf(xn.y); s4.z = f2bf(xn.z); s4.w = f2bf(xn.w);
  ((short4*)(xln + (size_t)t * H_DIM))[tid] = s4;
  __syncthreads();

  for (int e = 2 * wid; e < 2 * wid + 2; ++e) {
    float p = 0.f;
    for (int h = lane; h < H_DIM; h += 64) p += sx[h] * Wr[e * H_DIM + h];
    for (int o = 32; o > 0; o >>= 1) p += __shfl_down(p, o);
    if (lane == 0) slog[e] = p + br[e];
  }
  __syncthreads();

  if (tid == 0) {
    float lg[E_NUM];
    for (int e = 0; e < E_NUM; ++e) lg[e] = slog[e];
    int i0 = 0;
    for (int e = 1; e < E_NUM; ++e) if (lg[e] > lg[i0]) i0 = e;
    int i1 = (i0 == 0) ? 1 : 0;
    for (int e = 0; e < E_NUM; ++e) if (e != i0 && lg[e] > lg[i1]) i1 = e;
    float w1e = __expf(lg[i1] - lg[i0]);
    float den = 1.f + w1e;
    sel_e[2 * t] = i0; sel_w[2 * t] = 1.f / den;
    sel_e[2 * t + 1] = i1; sel_w[2 * t + 1] = w1e / den;
    float se = 0.f, pe[E_NUM];
    for (int e = 0; e < E_NUM; ++e) { pe[e] = __expf(lg[e] - lg[i0]); se += pe[e]; }
    float inv = 1.f / se;
    for (int e = 0; e < E_NUM; ++e) probs[t * E_NUM + e] = pe[e] * inv;
  }
}

// ---------------- K2: slot assignment + counts + tile table + loss ----------------
__global__ __launch_bounds__(512) void k_route(
    const int* __restrict__ sel_e, const float* __restrict__ sel_w,
    const float* __restrict__ probs,
    int* __restrict__ counts, int* __restrict__ basep,
    int* __restrict__ tile_e, int* __restrict__ tile_m0, int* __restrict__ ntiles,
    int* __restrict__ tlist, int* __restrict__ sel_idx,
    float* __restrict__ wslot, float* __restrict__ loss_out) {
  const int wid = threadIdx.x >> 6;
  const int lane = threadIdx.x & 63;
  __shared__ int scnt[E_NUM];
  __shared__ float susage[E_NUM];

  int cnt = 0;
  for (int s0 = 0; s0 < NSLOT; s0 += 64) {
    int s = s0 + lane;
    bool m = (sel_e[s] == wid);
    unsigned long long mk = __ballot(m);
    int pre = __popcll(mk & ((1ULL << lane) - 1ULL));
    if (m) {
      int idx = cnt + pre;
      sel_idx[s] = idx;
      tlist[wid * T_TOK + idx] = s >> 1;
      wslot[wid * T_TOK + idx] = sel_w[s];
    }
    cnt += __popcll(mk);
  }
  if (lane == 0) scnt[wid] = cnt;

  float u = 0.f;
  for (int t = lane; t < T_TOK; t += 64) u += probs[t * E_NUM + wid];
  for (int o = 32; o > 0; o >>= 1) u += __shfl_down(u, o);
  if (lane == 0) susage[wid] = u * (1.0f / T_TOK);
  __syncthreads();

  if (threadIdx.x == 0) {
    int b = 0, nt = 0;
    for (int e = 0; e < E_NUM; ++e) {
      basep[e] = b; counts[e] = scnt[e];
      int te = (scnt[e] + 127) >> 7;
      for (int i = 0; i < te && nt < MAXT; ++i) {
        tile_e[nt] = e; tile_m0[nt] = i * 128; ++nt;
      }
      b += te * 128;
    }
    ntiles[0] = nt;
    float sq = 0.f;
    for (int e = 0; e < E_NUM; ++e) sq += susage[e] * susage[e];
    *loss_out = (float)E_NUM * sq - 1.0f;
  }
}

// ---------------- standalone cvt+repack ----------------
__global__ __launch_bounds__(256) void k_cvtpack(const float* __restrict__ src,
                                                 short* __restrict__ dst,
                                                 int rsh, int csh) {
  cvtpack_dev(src, dst, blockIdx.x, gridDim.x, rsh, csh);
}

// ---------------- K3: GEMM1, flat dead-free grid; cvtW2 blocks FIRST ----------------
// bid < nc2: cvtpack(W2).  bid >= nc2: GEMM, tile = (bid-nc2)>>5, x = (bid-nc2)&31.
__global__ __launch_bounds__(256) void k_ffn1(
    const short* __restrict__ xln, const short* __restrict__ W1b,
    const float* __restrict__ b1, const int* __restrict__ counts,
    const int* __restrict__ basep,
    const int* __restrict__ tile_e, const int* __restrict__ tile_m0,
    const int* __restrict__ ntiles, const int* __restrict__ tlist,
    short* __restrict__ a_buf,
    const float* __restrict__ W2src, short* __restrict__ w2dst, int nc2) {
  const int bid = blockIdx.x;
  if (bid < nc2) {
    cvtpack_dev(W2src, w2dst, bid, nc2, 10, 12);   // rows=H, cols=I
    return;
  }
  const int gbid = bid - nc2;
  const int tileid = gbid >> 5;
  if (tileid >= ntiles[0]) return;
  const int e = tile_e[tileid];
  const int m0 = tile_m0[tileid];
  const int cnt = counts[e];
  const int n0 = (gbid & 31) * 128;

  __shared__ __align__(16) short As[3][128 * 32];
  __shared__ __align__(16) short Bs[3][128 * 32];

  const int tid = threadIdx.x;
  const int lane = tid & 63, wid = tid >> 6;
  const int wr = wid >> 1, wc = wid & 1;
  const int fr = lane & 15, fq = lane >> 4;

  int r0 = m0 + (tid >> 2); if (r0 >= cnt) r0 = cnt - 1;
  int r1 = m0 + 64 + (tid >> 2); if (r1 >= cnt) r1 = cnt - 1;
  const short* ag0 = xln + (size_t)tlist[e * T_TOK + r0] * H_DIM + (tid & 3) * 8;
  const short* ag1 = xln + (size_t)tlist[e * T_TOK + r1] * H_DIM + (tid & 3) * 8;
  const short* bgp = W1b + ((size_t)e << 22) + ((size_t)(n0 >> 7) * 131072) + tid * 8;

  f32x4 acc[4][4];
#pragma unroll
  for (int i = 0; i < 4; ++i)
#pragma unroll
    for (int j = 0; j < 4; ++j) acc[i][j] = (f32x4)0.f;

#define STAGE(kt, buf)                                          \
  {                                                             \
    glds16(ag0 + (kt) * 32, &As[buf][tid * 8]);                 \
    glds16(ag1 + (kt) * 32, &As[buf][(256 + tid) * 8]);         \
    glds16(bgp + (size_t)(kt) * 4096, &Bs[buf][tid * 8]);       \
    glds16(bgp + (size_t)(kt) * 4096 + 2048,                    \
           &Bs[buf][(256 + tid) * 8]);                          \
  }

  STAGE(0, 0);
  STAGE(1, 1);

  const int KT = H_DIM / 32;
  for (int kt = 0; kt < KT; ++kt) {
    if (kt == KT - 1) {
      asm volatile("s_waitcnt vmcnt(0)" ::: "memory");
    } else {
      asm volatile("s_waitcnt vmcnt(4)" ::: "memory");
    }
    __builtin_amdgcn_s_barrier();
    if (kt + 2 < KT) STAGE(kt + 2, (kt + 2) % 3);
    const int cb = kt % 3;
    bf16x8 af[4], bb[4];
#pragma unroll
    for (int mi = 0; mi < 4; ++mi)
      af[mi] = *(const bf16x8*)&As[cb][(wr * 64 + mi * 16 + fr) * 32 + fq * 8];
#pragma unroll
    for (int ni = 0; ni < 4; ++ni)
      bb[ni] = *(const bf16x8*)&Bs[cb][(wc * 64 + ni * 16 + fr) * 32 + fq * 8];
#pragma unroll
    for (int mi = 0; mi < 4; ++mi)
#pragma unroll
      for (int ni = 0; ni < 4; ++ni)
        acc[mi][ni] = MFMA_BF16(af[mi], bb[ni], acc[mi][ni]);
  }
#undef STAGE

  // epilogue: GELU, a_buf tile-packed [T][i>>5][r][i&31]
  const size_t T1 = (size_t)(basep[e] + m0) >> 7;
  short* abase = a_buf + T1 * 524288;
  float b1v[4];
#pragma unroll
  for (int ni = 0; ni < 4; ++ni)
    b1v[ni] = b1[e * I_DIM + n0 + wc * 64 + ni * 16 + fr];
#pragma unroll
  for (int mi = 0; mi < 4; ++mi)
#pragma unroll
    for (int j = 0; j < 4; ++j) {
      int r = wr * 64 + mi * 16 + fq * 4 + j;
      if (m0 + r < cnt) {
#pragma unroll
        for (int ni = 0; ni < 4; ++ni) {
          int colg = n0 + wc * 64 + ni * 16 + fr;
          float vv = acc[mi][ni][j] + b1v[ni];
          float g = 0.5f * vv * (1.0f + erff(vv * 0.70710678118654752f));
          abase[(size_t)(colg >> 5) * 4096 + r * 32 + (colg & 31)] = f2bf(g);
        }
      }
    }
}

// ---------------- K4: GEMM2, flat grid, split-K=4; y_part stores (or atomic fallback) ----------------
__global__ __launch_bounds__(256) void k_ffn2(
    const short* __restrict__ a_buf, const short* __restrict__ W2b,
    const float* __restrict__ b2, const int* __restrict__ counts,
    const int* __restrict__ basep,
    const int* __restrict__ tile_e, const int* __restrict__ tile_m0,
    const int* __restrict__ ntiles, const int* __restrict__ tlist,
    const float* __restrict__ wslot, float* __restrict__ y_part,
    float* __restrict__ out) {
  const int bid = blockIdx.x;
  const int tileid = bid >> 5;
  if (tileid >= ntiles[0]) return;
  const int rem = bid & 31;
  const int kc = rem >> 3;
  const int n0 = (rem & 7) * 128;
  const int e = tile_e[tileid];
  const int m0 = tile_m0[tileid];
  const int cnt = counts[e];

  __shared__ __align__(16) short As[3][128 * 32];
  __shared__ __align__(16) short Bs[3][128 * 32];

  const int tid = threadIdx.x;
  const int lane = tid & 63, wid = tid >> 6;
  const int wr = wid >> 1, wc = wid & 1;
  const int fr = lane & 15, fq = lane >> 4;

  const size_t T1 = (size_t)(basep[e] + m0) >> 7;
  const short* agp = a_buf + T1 * 524288 + (size_t)kc * 131072 + tid * 8;
  const short* bgp = W2b + ((size_t)e << 22) + ((size_t)(n0 >> 7) * 524288) +
                     (size_t)kc * 131072 + tid * 8;

  f32x4 acc[4][4];
#pragma unroll
  for (int i = 0; i < 4; ++i)
#pragma unroll
    for (int j = 0; j < 4; ++j) acc[i][j] = (f32x4)0.f;

#define STAGE(kt, buf)                                          \
  {                                                             \
    glds16(agp + (size_t)(kt) * 4096, &As[buf][tid * 8]);       \
    glds16(agp + (size_t)(kt) * 4096 + 2048,                    \
           &As[buf][(256 + tid) * 8]);                          \
    glds16(bgp + (size_t)(kt) * 4096, &Bs[buf][tid * 8]);       \
    glds16(bgp + (size_t)(kt) * 4096 + 2048,                    \
           &Bs[buf][(256 + tid) * 8]);                          \
  }

  STAGE(0, 0);
  STAGE(1, 1);

  const int KT = 32;
  for (int kt = 0; kt < KT; ++kt) {
    if (kt == KT - 1) {
      asm volatile("s_waitcnt vmcnt(0)" ::: "memory");
    } else {
      asm volatile("s_waitcnt vmcnt(4)" ::: "memory");
    }
    __builtin_amdgcn_s_barrier();
    if (kt + 2 < KT) STAGE(kt + 2, (kt + 2) % 3);
    const int cb = kt % 3;
    bf16x8 af[4], bb[4];
#pragma unroll
    for (int mi = 0; mi < 4; ++mi)
      af[mi] = *(const bf16x8*)&As[cb][(wr * 64 + mi * 16 + fr) * 32 + fq * 8];
#pragma unroll
    for (int ni = 0; ni < 4; ++ni)
      bb[ni] = *(const bf16x8*)&Bs[cb][(wc * 64 + ni * 16 + fr) * 32 + fq * 8];
#pragma unroll
    for (int mi = 0; mi < 4; ++mi)
#pragma unroll
      for (int ni = 0; ni < 4; ++ni)
        acc[mi][ni] = MFMA_BF16(af[mi], bb[ni], acc[mi][ni]);
  }
#undef STAGE

  const int slot0 = basep[e] + m0;
  if (y_part) {
    // plain stores; b2/router-weight/residual applied in k_combine
    float* yp = y_part + (size_t)kc * ((size_t)SLOTP * H_DIM);
#pragma unroll
    for (int mi = 0; mi < 4; ++mi)
#pragma unroll
      for (int j = 0; j < 4; ++j) {
        int r = wr * 64 + mi * 16 + fq * 4 + j;
        if (m0 + r < cnt) {
          size_t rowoff = (size_t)(slot0 + r) * H_DIM;
#pragma unroll
          for (int ni = 0; ni < 4; ++ni) {
            int colg = n0 + wc * 64 + ni * 16 + fr;
            yp[rowoff + colg] = acc[mi][ni][j];
          }
        }
      }
  } else {
    float b2v[4];
#pragma unroll
    for (int ni = 0; ni < 4; ++ni)
      b2v[ni] = 0.25f * b2[e * H_DIM + n0 + wc * 64 + ni * 16 + fr];
#pragma unroll
    for (int mi = 0; mi < 4; ++mi)
#pragma unroll
      for (int j = 0; j < 4; ++j) {
        int r = wr * 64 + mi * 16 + fq * 4 + j;
        if (m0 + r < cnt) {
          int tok = tlist[e * T_TOK + m0 + r];
          float w = wslot[e * T_TOK + m0 + r];
          float* orow = out + (size_t)tok * H_DIM;
#pragma unroll
          for (int ni = 0; ni < 4; ++ni) {
            int colg = n0 + wc * 64 + ni * 16 + fr;
            atomicAdd(&orow[colg], w * (acc[mi][ni][j] + b2v[ni]));
          }
        }
      }
  }
}

// ---------------- K5: combine split-K partials + bias + residual ----------------
__global__ __launch_bounds__(256) void k_combine(
    const float* __restrict__ hidden, const float* __restrict__ y_part,
    const float* __restrict__ b2, const int* __restrict__ basep,
    const int* __restrict__ sel_e, const int* __restrict__ sel_idx,
    const float* __restrict__ sel_w, float* __restrict__ out) {
  const int t = blockIdx.x;
  const int tid = threadIdx.x;
  int e0 = sel_e[2 * t], e1 = sel_e[2 * t + 1];
  size_t s0 = (size_t)basep[e0] + sel_idx[2 * t];
  size_t s1 = (size_t)basep[e1] + sel_idx[2 * t + 1];
  float w0 = sel_w[2 * t], w1 = sel_w[2 * t + 1];
  const size_t TY = (size_t)SLOTP * H_DIM;
  float4 y0 = make_float4(0.f, 0.f, 0.f, 0.f);
  float4 y1 = make_float4(0.f, 0.f, 0.f, 0.f);
  for (int kc = 0; kc < 4; ++kc) {
    float4 p0 = ((const float4*)(y_part + kc * TY + s0 * H_DIM))[tid];
    float4 p1 = ((const float4*)(y_part + kc * TY + s1 * H_DIM))[tid];
    y0.x += p0.x; y0.y += p0.y; y0.z += p0.z; y0.w += p0.w;
    y1.x += p1.x; y1.y += p1.y; y1.z += p1.z; y1.w += p1.w;
  }
  float4 be0 = ((const float4*)(b2 + (size_t)e0 * H_DIM))[tid];
  float4 be1 = ((const float4*)(b2 + (size_t)e1 * H_DIM))[tid];
  float4 r = ((const float4*)(hidden + (size_t)t * H_DIM))[tid];
  float4 o;
  o.x = r.x + w0 * (y0.x + be0.x) + w1 * (y1.x + be1.x);
  o.y = r.y + w0 * (y0.y + be0.y) + w1 * (y1.y + be1.y);
  o.z = r.z + w0 * (y0.z + be0.z) + w1 * (y1.z + be1.z);
  o.w = r.w + w0 * (y0.w + be0.w) + w1 * (y1.w + be1.w);
  ((float4*)(out + (size_t)t * H_DIM))[tid] = o;
}

// ================= Fallback (small ws): inline-cvt f32 kernels, linear a_buf =================
__global__ __launch_bounds__(256) void k_ffn1_f32(
    const short* __restrict__ xln, const float* __restrict__ W1,
    const float* __restrict__ b1, const int* __restrict__ counts,
    const int* __restrict__ basep, const int* __restrict__ tlist,
    short* __restrict__ a_buf) {
  const int e = blockIdx.z;
  const int cnt = counts[e];
  const int m0 = blockIdx.y * 128;
  if (m0 >= cnt) return;
  const int n0 = blockIdx.x * 128;
  __shared__ __align__(16) short As[2][128 * 32];
  __shared__ __align__(16) float Bsf[2][128 * 32];
  const int tid = threadIdx.x;
  const int lane = tid & 63, wid = tid >> 6;
  const int wr = wid >> 1, wc = wid & 1;
  const int fr = lane & 15, fq = lane >> 4;
  int r0 = m0 + (tid >> 2); if (r0 >= cnt) r0 = cnt - 1;
  int r1 = m0 + 64 + (tid >> 2); if (r1 >= cnt) r1 = cnt - 1;
  const short* ag0 = xln + (size_t)tlist[e * T_TOK + r0] * H_DIM + (tid & 3) * 8;
  const short* ag1 = xln + (size_t)tlist[e * T_TOK + r1] * H_DIM + (tid & 3) * 8;
  const int bro = tid >> 3;
  const int bslot = (tid & 7) ^ (bro & 7);
  const float* bg = W1 + ((size_t)e * I_DIM + n0 + bro) * H_DIM + bslot * 4;
  f32x4 acc[4][4];
#pragma unroll
  for (int i = 0; i < 4; ++i)
#pragma unroll
    for (int j = 0; j < 4; ++j) acc[i][j] = (f32x4)0.f;
#define STAGE(kk, buf)                                                      \
  {                                                                         \
    glds16(ag0 + (kk), &As[buf][tid * 8]);                                  \
    glds16(ag1 + (kk), &As[buf][(256 + tid) * 8]);                          \
    _Pragma("unroll") for (int i = 0; i < 4; ++i)                           \
        glds16(bg + (size_t)(i * 32) * H_DIM + (kk),                        \
               &Bsf[buf][(i * 256 + tid) * 4]);                             \
  }
  STAGE(0, 0);
  __syncthreads();
  int cur = 0;
  for (int kt = 0; kt < H_DIM / 32; ++kt) {
    if (kt + 1 < H_DIM / 32) STAGE((kt + 1) * 32, cur ^ 1);
    bf16x8 af[4], bb[4];
#pragma unroll
    for (int mi = 0; mi < 4; ++mi)
      af[mi] = *(const bf16x8*)&As[cur][(wr * 64 + mi * 16 + fr) * 32 + fq * 8];
#pragma unroll
    for (int ni = 0; ni < 4; ++ni) {
      const int row = wc * 64 + ni * 16 + fr;
      const int base = row * 128 + fq * 32;
      const int sw = (row & 7) << 4;
      f32x4 lo = *(const f32x4*)((const char*)&Bsf[cur][0] + (base ^ sw));
      f32x4 hi = *(const f32x4*)((const char*)&Bsf[cur][0] + ((base + 16) ^ sw));
      BBCast c;
      c.i4.x = pack2bf(lo[0], lo[1]); c.i4.y = pack2bf(lo[2], lo[3]);
      c.i4.z = pack2bf(hi[0], hi[1]); c.i4.w = pack2bf(hi[2], hi[3]);
      bb[ni] = c.v;
    }
#pragma unroll
    for (int mi = 0; mi < 4; ++mi)
#pragma unroll
      for (int ni = 0; ni < 4; ++ni)
        acc[mi][ni] = MFMA_BF16(af[mi], bb[ni], acc[mi][ni]);
    __syncthreads();
    cur ^= 1;
  }
#undef STAGE
  const int slot0 = basep[e] + m0;
  float b1v[4];
#pragma unroll
  for (int ni = 0; ni < 4; ++ni)
    b1v[ni] = b1[e * I_DIM + n0 + wc * 64 + ni * 16 + fr];
#pragma unroll
  for (int mi = 0; mi < 4; ++mi)
#pragma unroll
    for (int j = 0; j < 4; ++j) {
      int r = wr * 64 + mi * 16 + fq * 4 + j;
      if (m0 + r < cnt) {
        size_t rowoff = (size_t)(slot0 + r) * I_DIM;
#pragma unroll
        for (int ni = 0; ni < 4; ++ni) {
          int colg = n0 + wc * 64 + ni * 16 + fr;
          float vv = acc[mi][ni][j] + b1v[ni];
          float g = 0.5f * vv * (1.0f + erff(vv * 0.70710678118654752f));
          a_buf[rowoff + colg] = f2bf(g);
        }
      }
    }
}

__global__ __launch_bounds__(256) void k_ffn2_f32(
    const short* __restrict__ a_buf, const float* __restrict__ W2,
    const float* __restrict__ b2, const int* __restrict__ counts,
    const int* __restrict__ basep, const int* __restrict__ tlist,
    const float* __restrict__ wslot, float* __restrict__ out, int lg) {
  const int z = blockIdx.z;
  const int e = z >> lg;
  const int kc = z & ((1 << lg) - 1);
  const int CH = I_DIM >> lg;
  const int cnt = counts[e];
  const int m0 = blockIdx.y * 128;
  if (m0 >= cnt) return;
  const int n0 = blockIdx.x * 128;
  __shared__ __align__(16) short As[2][128 * 32];
  __shared__ __align__(16) float Bsf[2][128 * 32];
  const int tid = threadIdx.x;
  const int lane = tid & 63, wid = tid >> 6;
  const int wr = wid >> 1, wc = wid & 1;
  const int fr = lane & 15, fq = lane >> 4;
  int r0 = m0 + (tid >> 2); if (r0 >= cnt) r0 = cnt - 1;
  int r1 = m0 + 64 + (tid >> 2); if (r1 >= cnt) r1 = cnt - 1;
  const int sb = basep[e];
  const short* ag0 = a_buf + (size_t)(sb + r0) * I_DIM + kc * CH + (tid & 3) * 8;
  const short* ag1 = a_buf + (size_t)(sb + r1) * I_DIM + kc * CH + (tid & 3) * 8;
  const int bro = tid >> 3;
  const int bslot = (tid & 7) ^ (bro & 7);
  const float* bg = W2 + ((size_t)e * H_DIM + n0 + bro) * I_DIM + kc * CH + bslot * 4;
  f32x4 acc[4][4];
#pragma unroll
  for (int i = 0; i < 4; ++i)
#pragma unroll
    for (int j = 0; j < 4; ++j) acc[i][j] = (f32x4)0.f;
#define STAGE(kk, buf)                                                      \
  {                                                                         \
    glds16(ag0 + (kk), &As[buf][tid * 8]);                                  \
    glds16(ag1 + (kk), &As[buf][(256 + tid) * 8]);                          \
    _Pragma("unroll") for (int i = 0; i < 4; ++i)                           \
        glds16(bg + (size_t)(i * 32) * I_DIM + (kk),                        \
               &Bsf[buf][(i * 256 + tid) * 4]);                             \
  }
  STAGE(0, 0);
  __syncthreads();
  const int KT = CH / 32;
  int cur = 0;
  for (int kt = 0; kt < KT; ++kt) {
    if (kt + 1 < KT) STAGE((kt + 1) * 32, cur ^ 1);
    bf16x8 af[4], bb[4];
#pragma unroll
    for (int mi = 0; mi < 4; ++mi)
      af[mi] = *(const bf16x8*)&As[cur][(wr * 64 + mi * 16 + fr) * 32 + fq * 8];
#pragma unroll
    for (int ni = 0; ni < 4; ++ni) {
      const int row = wc * 64 + ni * 16 + fr;
      const int base = row * 128 + fq * 32;
      const int sw = (row & 7) << 4;
      f32x4 lo = *(const f32x4*)((const char*)&Bsf[cur][0] + (base ^ sw));
      f32x4 hi = *(const f32x4*)((const char*)&Bsf[cur][0] + ((base + 16) ^ sw));
      BBCast c;
      c.i4.x = pack2bf(lo[0], lo[1]); c.i4.y = pack2bf(lo[2], lo[3]);
      c.i4.z = pack2bf(hi[0], hi[1]); c.i4.w = pack2bf(hi[2], hi[3]);
      bb[ni] = c.v;
    }
#pragma unroll
    for (int mi = 0; mi < 4; ++mi)
#pragma unroll
      for (int ni = 0; ni < 4; ++ni)
        acc[mi][ni] = MFMA_BF16(af[mi], bb[ni], acc[mi][ni]);
    __syncthreads();
    cur ^= 1;
  }
#undef STAGE
  const float inv = 1.0f / (float)(1 << lg);
  float b2v[4];
#pragma unroll
  for (int ni = 0; ni < 4; ++ni)
    b2v[ni] = inv * b2[e * H_DIM + n0 + wc * 64 + ni * 16 + fr];
#pragma unroll
  for (int mi = 0; mi < 4; ++mi)
#pragma unroll
    for (int j = 0; j < 4; ++j) {
      int r = wr * 64 + mi * 16 + fq * 4 + j;
      if (m0 + r < cnt) {
        int tok = tlist[e * T_TOK + m0 + r];
        float w = wslot[e * T_TOK + m0 + r];
        float* orow = out + (size_t)tok * H_DIM;
#pragma unroll
        for (int ni = 0; ni < 4; ++ni) {
          int colg = n0 + wc * 64 + ni * 16 + fr;
          atomicAdd(&orow[colg], w * (acc[mi][ni][j] + b2v[ni]));
        }
      }
    }
}

extern "C" void kernel_launch(void* const* d_in, const int* in_sizes, int n_in,
                              void* d_out, int out_size, void* d_ws, size_t ws_size,
                              hipStream_t stream) {
  const float* hidden = (const float*)d_in[0];
  const float* ln_w = (const float*)d_in[1];
  const float* ln_b = (const float*)d_in[2];
  const float* Wr = (const float*)d_in[3];
  const float* br = (const float*)d_in[4];
  const float* W1 = (const float*)d_in[5];
  const float* b1 = (const float*)d_in[6];
  const float* W2 = (const float*)d_in[7];
  const float* b2 = (const float*)d_in[8];
  float* out = (float*)d_out;

  // workspace layout (bytes)
  char* w = (char*)d_ws;
  int* counts = (int*)(w + 0);
  int* basep = (int*)(w + 64);
  int* ntiles = (int*)(w + 128);
  int* tile_e = (int*)(w + 192);
  int* tile_m0 = (int*)(w + 320);
  float* probs = (float*)(w + 512);               // 32 KB
  int* tlist = (int*)(w + 33280);                 // 32 KB
  int* sel_e = (int*)(w + 66048);                 // 8 KB
  int* sel_idx = (int*)(w + 74240);               // 8 KB
  float* sel_w = (float*)(w + 82432);             // 8 KB
  float* wslot = (float*)(w + 90624);             // 8 KB
  short* xln = (short*)(w + 131072);              // 2 MB -> 2228224
  short* a_buf = (short*)(w + 2228224);           // 24 MB tile-packed -> 27394048
  short* w1_bf = (short*)(w + 27394048);          // 64 MB -> 94502912
  short* w2_bf = (short*)(w + 94502912);          // 64 MB -> 161611776
  float* y_part = (float*)w1_bf;                  // 48 MB, aliases w1_bf (dead by ffn2)
  const size_t REQ_SEQ = 94502912;
  const size_t REQ_FUSED = 161611776;

  if (ws_size >= REQ_SEQ) {
    const bool fused = (ws_size >= REQ_FUSED);
    k_pre<<<T_TOK + 1024, 256, 0, stream>>>(hidden, ln_w, ln_b, Wr, br, xln,
                                            sel_e, sel_w, probs, out, W1, w1_bf, 1024);
    k_route<<<1, 512, 0, stream>>>(sel_e, sel_w, probs, counts, basep,
                                   tile_e, tile_m0, ntiles, tlist, sel_idx,
                                   wslot, out + (size_t)T_TOK * H_DIM);
    if (fused) {
      // cvtW2 blocks FIRST (overlap with GEMM), then 768 GEMM blocks
      k_ffn1<<<256 + MAXT * 32, 256, 0, stream>>>(
          xln, w1_bf, b1, counts, basep, tile_e, tile_m0, ntiles, tlist, a_buf,
          W2, w2_bf, 256);
      // ffn2: plain stores into y_part (aliases dead w1_bf), then combine
      k_ffn2<<<MAXT * 32, 256, 0, stream>>>(
          a_buf, w2_bf, b2, counts, basep, tile_e, tile_m0, ntiles, tlist,
          wslot, y_part, out);
      k_combine<<<T_TOK, 256, 0, stream>>>(hidden, y_part, b2, basep,
                                           sel_e, sel_idx, sel_w, out);
    } else {
      // w2 reuses w1 buffer -> cannot alias y_part; use atomic epilogue
      k_ffn1<<<MAXT * 32, 256, 0, stream>>>(
          xln, w1_bf, b1, counts, basep, tile_e, tile_m0, ntiles, tlist, a_buf,
          nullptr, nullptr, 0);
      k_cvtpack<<<1024, 256, 0, stream>>>(W2, w1_bf, 10, 12);
      k_ffn2<<<MAXT * 32, 256, 0, stream>>>(
          a_buf, w1_bf, b2, counts, basep, tile_e, tile_m0, ntiles, tlist,
          wslot, nullptr, out);
    }
  } else {
    // tiny-ws fallback: inline f32 conversion GEMMs (linear a_buf)
    k_pre<<<T_TOK, 256, 0, stream>>>(hidden, ln_w, ln_b, Wr, br, xln,
                                     sel_e, sel_w, probs, out, nullptr, nullptr, 0);
    k_route<<<1, 512, 0, stream>>>(sel_e, sel_w, probs, counts, basep,
                                   tile_e, tile_m0, ntiles, tlist, sel_idx,
                                   wslot, out + (size_t)T_TOK * H_DIM);
    const int lg = 2;
    k_ffn1_f32<<<dim3(I_DIM / 128, T_TOK / 128, E_NUM), 256, 0, stream>>>(
        xln, W1, b1, counts, basep, tlist, a_buf);
    k_ffn2_f32<<<dim3(H_DIM / 128, T_TOK / 128, E_NUM << lg), 256, 0, stream>>>(
        a_buf, W2, b2, counts, basep, tlist, wslot, out, lg);
  }
}